// Round 9
// baseline (728.410 us; speedup 1.0000x reference)
//
#include <hip/hip_runtime.h>
#include <math.h>

#define TOK   8192
#define DDIM  1024
#define HDIM  4096
#define NEXP  8
#define CAP   17408   /* 16384 + 8*128 padding, = 136*128 */
#define NMT   136
#define BM    128
#define BN    128
#define BK    32      /* 64 bytes */

typedef __attribute__((ext_vector_type(8))) short  bfrag;
typedef __attribute__((ext_vector_type(4))) float  ffrag;
typedef __attribute__((ext_vector_type(8))) unsigned short us8;

__device__ __forceinline__ unsigned short f2bf(float f) {
  unsigned int u = __float_as_uint(f);
  u = (u + 0x7FFFu + ((u >> 16) & 1u)) >> 16;   // RNE
  return (unsigned short)u;
}
__device__ __forceinline__ float bf2f(unsigned short u) {
  return __uint_as_float((unsigned int)u << 16);
}

__device__ __forceinline__ void gll16(const void* g, void* l) {
  __builtin_amdgcn_global_load_lds(
      (const __attribute__((address_space(1))) unsigned int*)g,
      (__attribute__((address_space(3))) unsigned int*)l,
      16, 0, 0);
}

// ---- transpose+cvt v2: 4x4 register blocklets, b128 LDS both ways ----
// W1 [8][1024][4096], W2 [8][4096][1024] -> [C][R] bf16.
// Per thread: 4 float4 loads, 4 ds_write_b128, 4 ds_read_b128, 2 us8 stores.
// LDS [64][68] fp32: both b128 phases hit 8 lanes per bank-quad (optimal).
__global__ __launch_bounds__(256) void transpose_v2(const float* __restrict__ W1,
                                                    unsigned short* __restrict__ w1t,
                                                    const float* __restrict__ W2,
                                                    unsigned short* __restrict__ w2t) {
  int bid = blockIdx.x;
  const float* in; unsigned short* out; int R, C, tile;
  if (bid < 8192) { in = W1; out = w1t; R = DDIM; C = HDIM; tile = bid; }
  else            { in = W2; out = w2t; R = HDIM; C = DDIM; tile = bid - 8192; }
  int e = tile >> 10;
  int t = tile & 1023;
  int tpr = C >> 6;
  int ty = t / tpr, tx = t % tpr;
  size_t bo = (size_t)e * R * C;
  in += bo; out += bo;
  int r0 = ty * 64, c0 = tx * 64;

  __shared__ __align__(16) float T[64 * 68];
  int tid = threadIdx.x;
  int r4 = (tid >> 4) * 4;         // blocklet row
  int c4 = (tid & 15) * 4;         // blocklet col

  float4 v0 = *(const float4*)&in[(size_t)(r0 + r4 + 0) * C + c0 + c4];
  float4 v1 = *(const float4*)&in[(size_t)(r0 + r4 + 1) * C + c0 + c4];
  float4 v2 = *(const float4*)&in[(size_t)(r0 + r4 + 2) * C + c0 + c4];
  float4 v3 = *(const float4*)&in[(size_t)(r0 + r4 + 3) * C + c0 + c4];
  // register 4x4 transpose: column j of blocklet -> float4 along r
  float4 t0 = { v0.x, v1.x, v2.x, v3.x };
  float4 t1 = { v0.y, v1.y, v2.y, v3.y };
  float4 t2 = { v0.z, v1.z, v2.z, v3.z };
  float4 t3 = { v0.w, v1.w, v2.w, v3.w };
  *(float4*)&T[(c4 + 0) * 68 + r4] = t0;
  *(float4*)&T[(c4 + 1) * 68 + r4] = t1;
  *(float4*)&T[(c4 + 2) * 68 + r4] = t2;
  *(float4*)&T[(c4 + 3) * 68 + r4] = t3;
  __syncthreads();

  int oc = tid >> 2;               // 0..63 (transposed row = original col)
  int kg = (tid & 3) * 16;         // 16 fp32 along original r
  float4 f0 = *(const float4*)&T[oc * 68 + kg + 0];
  float4 f1 = *(const float4*)&T[oc * 68 + kg + 4];
  float4 f2 = *(const float4*)&T[oc * 68 + kg + 8];
  float4 f3 = *(const float4*)&T[oc * 68 + kg + 12];
  us8 a, b;
  a[0] = (short)f2bf(f0.x); a[1] = (short)f2bf(f0.y);
  a[2] = (short)f2bf(f0.z); a[3] = (short)f2bf(f0.w);
  a[4] = (short)f2bf(f1.x); a[5] = (short)f2bf(f1.y);
  a[6] = (short)f2bf(f1.z); a[7] = (short)f2bf(f1.w);
  b[0] = (short)f2bf(f2.x); b[1] = (short)f2bf(f2.y);
  b[2] = (short)f2bf(f2.z); b[3] = (short)f2bf(f2.w);
  b[4] = (short)f2bf(f3.x); b[5] = (short)f2bf(f3.y);
  b[6] = (short)f2bf(f3.z); b[7] = (short)f2bf(f3.w);
  *(us8*)&out[(size_t)(c0 + oc) * R + r0 + kg + 0] = a;
  *(us8*)&out[(size_t)(c0 + oc) * R + r0 + kg + 8] = b;
}

// ---- gate v2: Wg staged transposed in LDS (aligned float4 reads) ----
// 4 tokens per 256-thread block; logits fp32, top-2, softmax, x->bf16;
// also clears token_of.
__global__ __launch_bounds__(256) void gate_v2(const float* __restrict__ x,
                                               const float* __restrict__ Wg,
                                               const float* __restrict__ bg,
                                               unsigned short* __restrict__ xb,
                                               int* __restrict__ topi,
                                               float* __restrict__ topw,
                                               int* __restrict__ cnt,
                                               int* __restrict__ token_of) {
  __shared__ __align__(16) float wgT[NEXP * DDIM];   // [e][d], 32 KB
  int tid = threadIdx.x;
  // stage Wg [1024][8] -> wgT [8][1024]; writes 2-way bank (free)
#pragma unroll
  for (int it = 0; it < 8; ++it) {
    int gw = it * 1024 + tid * 4;        // word index into Wg
    float4 v = *(const float4*)&Wg[gw];
    int d = gw >> 3, e0 = gw & 7;
    wgT[(e0 + 0) * DDIM + d] = v.x;
    wgT[(e0 + 1) * DDIM + d] = v.y;
    wgT[(e0 + 2) * DDIM + d] = v.z;
    wgT[(e0 + 3) * DDIM + d] = v.w;
  }
  int gid = blockIdx.x * 256 + tid;
  if (gid < CAP) token_of[gid] = -1;
  __syncthreads();

  int w = tid >> 6, l = tid & 63;
  int t = blockIdx.x * 4 + w;
  const float4* xr = (const float4*)(x + (size_t)t * DDIM);
  ushort4* xo = (ushort4*)(xb + (size_t)t * DDIM);
  float acc[8];
#pragma unroll
  for (int e = 0; e < 8; ++e) acc[e] = 0.f;
#pragma unroll
  for (int g = 0; g < 4; ++g) {
    int idx = g * 64 + l;
    float4 xv = xr[idx];
    xo[idx] = (ushort4){ f2bf(xv.x), f2bf(xv.y), f2bf(xv.z), f2bf(xv.w) };
    int dbase = idx * 4;
#pragma unroll
    for (int e = 0; e < 8; ++e) {
      float4 wv = *(const float4*)&wgT[e * DDIM + dbase];   // aligned, 8/quad
      acc[e] += xv.x * wv.x + xv.y * wv.y + xv.z * wv.z + xv.w * wv.w;
    }
  }
#pragma unroll
  for (int off = 32; off >= 1; off >>= 1)
#pragma unroll
    for (int e = 0; e < 8; ++e) acc[e] += __shfl_down(acc[e], off);
  if (l == 0) {
    float v[8];
#pragma unroll
    for (int e = 0; e < 8; ++e) v[e] = acc[e] + bg[e];
    int i0 = 0;
#pragma unroll
    for (int e = 1; e < 8; ++e) if (v[e] > v[i0]) i0 = e;
    int i1 = -1;
#pragma unroll
    for (int e = 0; e < 8; ++e) if (e != i0 && (i1 < 0 || v[e] > v[i1])) i1 = e;
    float e1 = expf(v[i1] - v[i0]);
    float s = 1.f + e1;
    topi[t * 2 + 0] = i0; topi[t * 2 + 1] = i1;
    topw[t * 2 + 0] = 1.f / s; topw[t * 2 + 1] = e1 / s;
    atomicAdd(&cnt[i0], 1);
    atomicAdd(&cnt[i1], 1);
  }
}

// local 128-aligned exclusive scan of cnt (uniform, 8 entries)
__device__ __forceinline__ void local_scan(const int* __restrict__ cnt, int* offs) {
  int o = 0;
#pragma unroll
  for (int e = 0; e < NEXP; ++e) {
    offs[e] = o;
    o += ((cnt[e] + 127) >> 7) << 7;
  }
  offs[NEXP] = o;
}

// ---------------- assign rows (local scan) ----------------
__global__ __launch_bounds__(256) void assign_kernel(const int* __restrict__ topi,
                                                     const int* __restrict__ cnt,
                                                     int* __restrict__ cursor,
                                                     int* __restrict__ row_of,
                                                     int* __restrict__ token_of) {
  int offs[NEXP + 1];
  local_scan(cnt, offs);
  int id = blockIdx.x * 256 + threadIdx.x;
  if (id >= TOK * 2) return;
  int e = topi[id];
  int slot = atomicAdd(&cursor[e], 1);
  int row = offs[e] + slot;
  row_of[id] = row;
  token_of[row] = id >> 1;
}

// ---- grouped GEMM (r7 structure: 3-buffer counted-vmcnt + 2-way swizzle,
//      + L2-chunked XCD-aware block ordering) ----
template<bool INDIRECT, bool GELU>
__global__ __launch_bounds__(256)
void moe_gemm(const unsigned short* __restrict__ A,
              const unsigned short* __restrict__ B0,
              const float* __restrict__ bias0,
              unsigned short* __restrict__ out,
              int N, int K,
              const int* __restrict__ cnt,
              const int* __restrict__ token_of) {
  int offsets[NEXP + 1];
  local_scan(cnt, offsets);

  // XCD-chunked bijective swizzle with 8-wide N-tile grouping
  int nwg = gridDim.x * gridDim.y;
  int orig = blockIdx.y * gridDim.x + blockIdx.x;
  int V = nwg >> 3;
  int vid = (orig & 7) * V + (orig >> 3);
  int xcd = vid / V;
  int vloc = vid - xcd * V;
  int P = V / gridDim.x;
  int CW = gridDim.x >= 8 ? 8 : gridDim.x;
  int per = P * CW;
  int g = vloc / per;
  int rem = vloc - g * per;
  int m = rem / CW;
  int bx = g * CW + (rem - m * CW);
  int by = xcd * P + m;

  int row0 = by * BM;
  if (row0 >= offsets[NEXP]) return;
  int e = 0;
  while (row0 >= offsets[e + 1]) ++e;
  const unsigned short* B = B0 + (size_t)e * N * K;
  const float* bias = bias0 + (size_t)e * N;
  int n0 = bx * BN;

  __shared__ __align__(16) char sm[49152];

  int tid = threadIdx.x;
  int w = tid >> 6, l = tid & 63;
  int lrow = l & 15, kq = l >> 4;
  int wm = w >> 1, wn = w & 1;

  int c2 = (l & 7) ^ (l >> 3);
  int rloc = ((l >> 3) << 1) + (c2 >> 2);
  int ksw = (c2 & 3) * 16;
  int s0 = 2 * w, s1 = 2 * w + 1;

  int gr0 = row0 + s0 * 16 + rloc, gr1 = row0 + s1 * 16 + rloc;
  int ar0, ar1;
  if (INDIRECT) {
    int t0 = token_of[gr0]; ar0 = t0 < 0 ? 0 : t0;
    int t1 = token_of[gr1]; ar1 = t1 < 0 ? 0 : t1;
  } else { ar0 = gr0; ar1 = gr1; }
  const char* srcA0 = (const char*)(A + (size_t)ar0 * K) + ksw;
  const char* srcA1 = (const char*)(A + (size_t)ar1 * K) + ksw;
  const char* srcB0 = (const char*)(B + (size_t)(n0 + s0 * 16 + rloc) * K) + ksw;
  const char* srcB1 = (const char*)(B + (size_t)(n0 + s1 * 16 + rloc) * K) + ksw;

  auto stage = [&](int buf, int kb) {
    gll16(srcA0 + kb, sm + buf * 8192 + s0 * 1024);
    gll16(srcA1 + kb, sm + buf * 8192 + s1 * 1024);
    gll16(srcB0 + kb, sm + 24576 + buf * 8192 + s0 * 1024);
    gll16(srcB1 + kb, sm + 24576 + buf * 8192 + s1 * 1024);
  };

  int offA[4], offB[4];
#pragma unroll
  for (int i = 0; i < 4; ++i) {
    int ra = wm * 64 + i * 16 + lrow;
    offA[i] = (ra >> 1) * 128 + (((((ra & 1) << 2) + kq) ^ ((ra >> 1) & 7)) << 4);
    int rb = wn * 64 + i * 16 + lrow;
    offB[i] = 24576 + (rb >> 1) * 128 + (((((rb & 1) << 2) + kq) ^ ((rb >> 1) & 7)) << 4);
  }

  ffrag acc[4][4];
#pragma unroll
  for (int i = 0; i < 4; ++i)
#pragma unroll
    for (int j = 0; j < 4; ++j) acc[i][j] = (ffrag){0.f, 0.f, 0.f, 0.f};

  auto compute = [&](int buf) {
    int ab = buf * 8192;
    bfrag a[4], b[4];
#pragma unroll
    for (int i = 0; i < 4; ++i) a[i] = *(const bfrag*)(sm + ab + offA[i]);
#pragma unroll
    for (int j = 0; j < 4; ++j) b[j] = *(const bfrag*)(sm + ab + offB[j]);
#pragma unroll
    for (int i = 0; i < 4; ++i)
#pragma unroll
      for (int j = 0; j < 4; ++j)
        acc[i][j] = __builtin_amdgcn_mfma_f32_16x16x32_bf16(a[i], b[j], acc[i][j], 0, 0, 0);
  };

  stage(0, 0); stage(1, 64);
  asm volatile("s_waitcnt vmcnt(4)" ::: "memory");
  __builtin_amdgcn_s_barrier();

  int nk = K / BK;
  int cur = 0;
  for (int kt = 0; kt < nk; ++kt) {
    int nxt2 = cur + 2; if (nxt2 >= 3) nxt2 -= 3;
    if (kt + 2 < nk) stage(nxt2, (kt + 2) * 64);
    compute(cur);
    if (kt + 1 < nk) {
      if (kt + 2 < nk) { asm volatile("s_waitcnt vmcnt(4)" ::: "memory"); }
      else             { asm volatile("s_waitcnt vmcnt(0)" ::: "memory"); }
    }
    __builtin_amdgcn_s_barrier();
    ++cur; if (cur == 3) cur = 0;
  }

  unsigned short* ht = (unsigned short*)sm;   // [128][128] bf16 = 32 KB
#pragma unroll
  for (int j = 0; j < 4; ++j) {
    int col = wn * 64 + j * 16 + lrow;
    float bj = bias[n0 + col];
#pragma unroll
    for (int i = 0; i < 4; ++i) {
      int rl = wm * 64 + i * 16 + kq * 4;
#pragma unroll
      for (int r = 0; r < 4; ++r) {
        float v = acc[i][j][r] + bj;
        if (GELU) {
          float z = 1.5957691216f * (v + 0.044715f * v * v * v);
          v = v / (1.0f + __expf(-z));
        }
        ht[(rl + r) * BN + col] = f2bf(v);
      }
    }
  }
  __syncthreads();
#pragma unroll
  for (int it = 0; it < 8; ++it) {
    int c = it * 256 + tid;
    int row = c >> 4;
    int cc = (c & 15) * 8;
    us8 v = *(const us8*)&ht[row * BN + cc];
    *(us8*)&out[(size_t)(row0 + row) * N + n0 + cc] = v;
  }
}

// ---------------- combine (y is bf16) ----------------
__global__ __launch_bounds__(256) void combine_kernel(const unsigned short* __restrict__ y,
                                                      const int* __restrict__ row_of,
                                                      const float* __restrict__ topw,
                                                      float* __restrict__ out) {
  int t = blockIdx.x;
  int r0 = row_of[t * 2 + 0], r1 = row_of[t * 2 + 1];
  float w0 = topw[t * 2 + 0], w1 = topw[t * 2 + 1];
  const ushort4* y0 = (const ushort4*)(y + (size_t)r0 * DDIM);
  const ushort4* y1 = (const ushort4*)(y + (size_t)r1 * DDIM);
  float4* o = (float4*)(out + (size_t)t * DDIM);
  int i = threadIdx.x;
  ushort4 a = y0[i], b = y1[i];
  float4 r = { w0 * bf2f(a.x) + w1 * bf2f(b.x), w0 * bf2f(a.y) + w1 * bf2f(b.y),
               w0 * bf2f(a.z) + w1 * bf2f(b.z), w0 * bf2f(a.w) + w1 * bf2f(b.w) };
  o[i] = r;
}

extern "C" void kernel_launch(void* const* d_in, const int* in_sizes, int n_in,
                              void* d_out, int out_size, void* d_ws, size_t ws_size,
                              hipStream_t stream) {
  const float* x  = (const float*)d_in[0];
  const float* Wg = (const float*)d_in[1];
  const float* bg = (const float*)d_in[2];
  const float* W1 = (const float*)d_in[3];
  const float* b1 = (const float*)d_in[4];
  const float* W2 = (const float*)d_in[5];
  const float* b2 = (const float*)d_in[6];
  float* out = (float*)d_out;

  size_t off = 0;
  char* base = (char*)d_ws;
  auto alloc = [&](size_t bytes) -> void* {
    void* p = base + off;
    off += (bytes + 255) & ~(size_t)255;
    return p;
  };
  unsigned short* xb  = (unsigned short*)alloc((size_t)TOK * DDIM * 2);
  unsigned short* w1t = (unsigned short*)alloc((size_t)NEXP * HDIM * DDIM * 2);
  unsigned short* w2t = (unsigned short*)alloc((size_t)NEXP * DDIM * HDIM * 2);
  unsigned short* h   = (unsigned short*)alloc((size_t)CAP * HDIM * 2);
  unsigned short* y   = (unsigned short*)alloc((size_t)CAP * DDIM * 2);
  int*   topi     = (int*)alloc((size_t)TOK * 2 * 4);
  float* topw     = (float*)alloc((size_t)TOK * 2 * 4);
  int*   row_of   = (int*)alloc((size_t)TOK * 2 * 4);
  int*   token_of = (int*)alloc((size_t)CAP * 4);
  int*   cntcur   = (int*)alloc(64);      // cnt = [0..7], cursor = [8..15]
  if (off > ws_size) return;

  int* cnt = cntcur;
  int* cursor = cntcur + 8;

  hipMemsetAsync(cntcur, 0, 64, stream);

  gate_v2<<<TOK / 4, 256, 0, stream>>>(x, Wg, bg, xb, topi, topw, cnt, token_of);
  transpose_v2<<<16384, 256, 0, stream>>>(W1, w1t, W2, w2t);
  assign_kernel<<<(TOK * 2) / 256, 256, 0, stream>>>(topi, cnt, cursor,
                                                     row_of, token_of);

  moe_gemm<true, true><<<dim3(HDIM / BN, NMT), 256, 0, stream>>>(
      xb, w1t, b1, h, HDIM, DDIM, cnt, token_of);
  moe_gemm<false, false><<<dim3(DDIM / BN, NMT), 256, 0, stream>>>(
      h, w2t, b2, y, DDIM, HDIM, cnt, token_of);

  combine_kernel<<<TOK, 256, 0, stream>>>(y, row_of, topw, out);
}